// Round 4
// baseline (303.257 us; speedup 1.0000x reference)
//
#include <hip/hip_runtime.h>

typedef unsigned short u16;
typedef unsigned int u32;
typedef _Float16 half8 __attribute__((ext_vector_type(8)));
typedef __fp16 fp16x2 __attribute__((ext_vector_type(2)));
typedef float f32x16 __attribute__((ext_vector_type(16)));

union HU { uint4 u; half8 h; };
union PK { fp16x2 h; u32 u; };

__device__ __forceinline__ u16 f2h(float f) {
  union { _Float16 h; u16 u; } c;
  c.h = (_Float16)f;
  return c.u;
}

// Pack weights (O=64, I=64, 3, 3) fp32 -> fp16 in exact A-fragment order:
// wbuf[((t*2 + mt)*64 + lane)*8 + j] = w[m][c][rs]
//   m = mt*32 + (lane&31), k = t*16 + (lane>>5)*8 + j, rs = k>>6, c = k&63
// K ordering: k = rs*64 + c  (rs-major, c-minor); rs = kh*3+kw
__global__ void prep_w(const float* __restrict__ w, u16* __restrict__ wbuf) {
  int idx = blockIdx.x * 256 + threadIdx.x;  // 36864 total
  int j    = idx & 7;
  int lane = (idx >> 3) & 63;
  int mt   = (idx >> 9) & 1;
  int t    = idx >> 10;
  int m  = mt * 32 + (lane & 31);
  int k  = t * 16 + (lane >> 5) * 8 + j;
  int rs = k >> 6;
  int c  = k & 63;
  wbuf[idx] = f2h(w[(m * 64 + c) * 9 + rs]);
}

// Implicit-GEMM conv: M = O = 64 (2 mtiles), N = pixels, K = 576.
// Block: one n, 2 output rows, 128 w, all 64 o. 256 threads = 4 waves.
// K split into 2 c-half phases (channels 0-31, 32-63); acc persists across phases.
// LDS per phase: [slab = row(4)*4 + cblk(4)][w 128][c 8] fp16 = 32 KB -> 4 blocks/CU.
// Wave = (rw = wave>>1 row, np = wave&1 pixel-half): 64 px x 64 o -> 4 MFMA per 2A+2B loads.
__global__ __launch_bounds__(256, 4) void conv_mfma(
    const float* __restrict__ x, const u16* __restrict__ wbuf,
    const float* __restrict__ bias, float* __restrict__ out) {
  __shared__ u16 xlds[16 * 128 * 8];  // 32 KB

  int tid = threadIdx.x;
  int lane = tid & 63;
  int wave = tid >> 6;  // 0..3
  int bid = blockIdx.x;
  int nb = bid & 31;   // batch
  int hg = bid >> 5;   // row-group [0,64)
  int h0 = hg * 2;

  int l31 = lane & 63 & 31;
  int half = lane >> 5;
  int rw = wave >> 1;            // output row within block
  int p0 = (wave & 1) * 64 + l31;  // pixel of ntile 0
  int p1 = p0 + 32;                // pixel of ntile 1

  f32x16 acc[2][2] = {};  // [mt][nt]

#pragma unroll
  for (int ph = 0; ph < 2; ++ph) {
    if (ph) __syncthreads();  // previous K-loop must finish reading LDS

    // ---- stage x rows h0-1..h0+2, channels ph*32..ph*32+31 -> LDS ----
    // slab = row*4 + cblk (16 slabs); wave handles 4; lane covers w, w+64.
#pragma unroll
    for (int s = 0; s < 4; ++s) {
      int id = wave * 4 + s;   // 0..15
      int row = id >> 2;       // 0..3
      int cblk = id & 3;
      int hin = h0 - 1 + row;
      int c0 = ph * 32 + cblk * 8;
      bool inb = (hin >= 0 && hin < 128);
      const float* base = x + (((size_t)(nb * 64 + c0) * 128 + hin) * 128);
#pragma unroll
      for (int w2 = 0; w2 < 2; ++w2) {
        int w = w2 * 64 + lane;
        uint4 v = make_uint4(0u, 0u, 0u, 0u);
        if (inb) {
          float f[8];
#pragma unroll
          for (int j = 0; j < 8; ++j) f[j] = base[(size_t)j * 16384 + w];
          PK q0, q1, q2, q3;
          q0.h = __builtin_amdgcn_cvt_pkrtz(f[0], f[1]);
          q1.h = __builtin_amdgcn_cvt_pkrtz(f[2], f[3]);
          q2.h = __builtin_amdgcn_cvt_pkrtz(f[4], f[5]);
          q3.h = __builtin_amdgcn_cvt_pkrtz(f[6], f[7]);
          v = make_uint4(q0.u, q1.u, q2.u, q3.u);
        }
        *(uint4*)&xlds[(id * 128 + w) * 8] = v;
      }
    }
    __syncthreads();

    // ---- K-loop: 18 ktiles this phase ----
#pragma unroll
    for (int r = 0; r < 3; ++r) {
      int rowl = rw + r;  // LDS row index
#pragma unroll
      for (int s = 0; s < 3; ++s) {
        int pin0 = p0 + s - 1;
        int pin1 = p1 + s - 1;
        bool ob0 = (unsigned)pin0 >= 128u;
        bool ob1 = (unsigned)pin1 >= 128u;
        int pc0 = ob0 ? 0 : pin0;
        int pc1 = ob1 ? 0 : pin1;

        HU a[2][2], b[2][2];  // [tcl][mt] / [tcl][nt]
#pragma unroll
        for (int tcl = 0; tcl < 2; ++tcl) {
          int t = (r * 3 + s) * 4 + ph * 2 + tcl;
          int cblk = tcl * 2 + half;  // clocal = tcl*16 + half*8
          b[tcl][0].u = *(const uint4*)&xlds[((rowl * 4 + cblk) * 128 + pc0) * 8];
          b[tcl][1].u = *(const uint4*)&xlds[((rowl * 4 + cblk) * 128 + pc1) * 8];
          a[tcl][0].u = *(const uint4*)&wbuf[(t * 2 + 0) * 512 + lane * 8];
          a[tcl][1].u = *(const uint4*)&wbuf[(t * 2 + 1) * 512 + lane * 8];
          if (ob0) b[tcl][0].u = make_uint4(0u, 0u, 0u, 0u);
          if (ob1) b[tcl][1].u = make_uint4(0u, 0u, 0u, 0u);
        }
#pragma unroll
        for (int tcl = 0; tcl < 2; ++tcl) {
          acc[0][0] = __builtin_amdgcn_mfma_f32_32x32x16_f16(a[tcl][0].h, b[tcl][0].h, acc[0][0], 0, 0, 0);
          acc[0][1] = __builtin_amdgcn_mfma_f32_32x32x16_f16(a[tcl][0].h, b[tcl][1].h, acc[0][1], 0, 0, 0);
          acc[1][0] = __builtin_amdgcn_mfma_f32_32x32x16_f16(a[tcl][1].h, b[tcl][0].h, acc[1][0], 0, 0, 0);
          acc[1][1] = __builtin_amdgcn_mfma_f32_32x32x16_f16(a[tcl][1].h, b[tcl][1].h, acc[1][1], 0, 0, 0);
        }
      }
    }
  }

  // ---- epilogue: C/D layout col = lane&31 (pixel), row = (reg&3)+8*(reg>>2)+4*half (o) ----
  int h = h0 + rw;
  size_t outbase = (size_t)nb * 64 * 16384 + (size_t)h * 128;
#pragma unroll
  for (int nt = 0; nt < 2; ++nt) {
    int p = nt ? p1 : p0;
#pragma unroll
    for (int mt = 0; mt < 2; ++mt) {
#pragma unroll
      for (int reg = 0; reg < 16; ++reg) {
        int o = mt * 32 + (reg & 3) + 8 * (reg >> 2) + 4 * half;
        out[outbase + (size_t)o * 16384 + p] = acc[mt][nt][reg] + bias[o];
      }
    }
  }
}

extern "C" void kernel_launch(void* const* d_in, const int* in_sizes, int n_in,
                              void* d_out, int out_size, void* d_ws, size_t ws_size,
                              hipStream_t stream) {
  const float* x = (const float*)d_in[0];
  const float* w = (const float*)d_in[1];
  const float* b = (const float*)d_in[2];
  float* out = (float*)d_out;
  u16* wbuf = (u16*)d_ws;  // 36864 fp16 = 73728 B of scratch

  prep_w<<<dim3(144), dim3(256), 0, stream>>>(w, wbuf);
  conv_mfma<<<dim3(2048), dim3(256), 0, stream>>>(x, wbuf, b, out);
}